// Round 1
// baseline (275.851 us; speedup 1.0000x reference)
//
#include <hip/hip_runtime.h>
#include <hip/hip_bf16.h>
#include <cstdint>
#include <cstddef>

typedef __bf16 bf16x8 __attribute__((ext_vector_type(8)));
typedef float f32x4 __attribute__((ext_vector_type(4)));

#define DI __device__ __forceinline__

DI unsigned short f2bf(float x) {
    union { float f; unsigned int u; } v; v.f = x;
    unsigned int u = v.u;
    u += 0x7FFFu + ((u >> 16) & 1u);
    return (unsigned short)(u >> 16);
}

#define BATCH 64
#define NH 12
#define NTOK 197
#define NTOK_P 208   // 13*16
#define HD 64
#define DIM 768
#define MROWS 12608  // BATCH*NTOK
#define MPAD 224     // 7*32 padded kv length for PV

// ---------------- prep kernels ----------------

__global__ void cvt_bf16_kernel(const float* __restrict__ in, unsigned short* __restrict__ out, int n4) {
    int i = blockIdx.x * blockDim.x + threadIdx.x;
    if (i >= n4) return;
    float4 f = ((const float4*)in)[i];
    ushort4 o;
    o.x = f2bf(f.x); o.y = f2bf(f.y); o.z = f2bf(f.z); o.w = f2bf(f.w);
    ((ushort4*)out)[i] = o;
}

__global__ void build_rpb_kernel(const float* __restrict__ table, const int* __restrict__ idx,
                                 float* __restrict__ out) {
    int i = blockIdx.x * blockDim.x + threadIdx.x;
    if (i >= NH * NTOK_P * NTOK_P) return;
    int c = i % NTOK_P; int r = (i / NTOK_P) % NTOK_P; int h = i / (NTOK_P * NTOK_P);
    float v = 0.f;
    if (r < NTOK && c < NTOK) v = table[idx[r * NTOK + c] * NH + h];
    out[i] = v;
}

__global__ void zero_vt_pad_kernel(unsigned short* __restrict__ vt) {
    const int npad = MPAD - NTOK; // 27
    int i = blockIdx.x * blockDim.x + threadIdx.x;
    if (i >= BATCH * NH * HD * npad) return;
    int c = NTOK + (i % npad);
    int row = i / npad;
    vt[(size_t)row * MPAD + c] = 0;
}

// ---------------- NT GEMM: C[m,n] = sum_k A[m,k]*W[n,k], K=768 ----------------
// EPI 0: qkv epilogue (bias + scale, scatter to q/k/vt bf16)
// EPI 1: proj epilogue (bias, fp32 to d_out)

template<int EPI>
__launch_bounds__(256)
__global__ void gemm_bt_kernel(const unsigned short* __restrict__ A,
                               const unsigned short* __restrict__ W,
                               const float* __restrict__ bias0,
                               const float* __restrict__ bias1,
                               void* __restrict__ out0,
                               unsigned short* __restrict__ out1,
                               unsigned short* __restrict__ out2,
                               int M, int ntiles)
{
    __shared__ __align__(16) unsigned short As[128 * 64];
    __shared__ __align__(16) unsigned short Bs[128 * 64];
    const int K = DIM;
    int bid = blockIdx.x;
    int mt = bid / ntiles, nt = bid % ntiles;
    int m0 = mt * 128, n0 = nt * 128;
    int tid = threadIdx.x;
    int lane = tid & 63, w = tid >> 6;
    int wr = (w >> 1) * 64, wc = (w & 1) * 64;

    f32x4 acc[4][4] = {};

    for (int ks = 0; ks < K; ks += 64) {
#pragma unroll
        for (int i = 0; i < 4; i++) {
            int e = ((w * 4 + i) * 64 + lane) * 8;
            int row = e >> 6, col = e & 63;
            int arow = m0 + row; if (arow >= M) arow = M - 1;
            __builtin_amdgcn_global_load_lds(
                (const __attribute__((address_space(1))) void*)(A + (size_t)arow * K + ks + col),
                (__attribute__((address_space(3))) void*)(As + (w * 4 + i) * 512),
                16, 0, 0);
        }
#pragma unroll
        for (int i = 0; i < 4; i++) {
            int e = ((w * 4 + i) * 64 + lane) * 8;
            int row = e >> 6, col = e & 63;
            __builtin_amdgcn_global_load_lds(
                (const __attribute__((address_space(1))) void*)(W + (size_t)(n0 + row) * K + ks + col),
                (__attribute__((address_space(3))) void*)(Bs + (w * 4 + i) * 512),
                16, 0, 0);
        }
        __syncthreads();
#pragma unroll
        for (int kc = 0; kc < 2; kc++) {
            bf16x8 af[4], bfr[4];
#pragma unroll
            for (int x = 0; x < 4; x++)
                af[x] = *(const bf16x8*)&As[(wr + x * 16 + (lane & 15)) * 64 + kc * 32 + (lane >> 4) * 8];
#pragma unroll
            for (int y = 0; y < 4; y++)
                bfr[y] = *(const bf16x8*)&Bs[(wc + y * 16 + (lane & 15)) * 64 + kc * 32 + (lane >> 4) * 8];
#pragma unroll
            for (int x = 0; x < 4; x++)
#pragma unroll
                for (int y = 0; y < 4; y++)
                    acc[x][y] = __builtin_amdgcn_mfma_f32_16x16x32_bf16(af[x], bfr[y], acc[x][y], 0, 0, 0);
        }
        __syncthreads();
    }

#pragma unroll
    for (int x = 0; x < 4; x++) {
#pragma unroll
        for (int y = 0; y < 4; y++) {
#pragma unroll
            for (int j = 0; j < 4; j++) {
                int m = m0 + wr + x * 16 + (lane >> 4) * 4 + j;
                int n = n0 + wc + y * 16 + (lane & 15);
                if (m >= M) continue;
                float val = acc[x][y][j];
                if constexpr (EPI == 0) {
                    int b = m / NTOK, t = m - (m / NTOK) * NTOK;
                    int which = n / DIM;
                    int hn = n - which * DIM;
                    int h = hn >> 6, d = hn & 63;
                    size_t bh = (size_t)b * NH + h;
                    if (which == 0) {
                        val = (val + bias0[hn]) * 0.125f; // 64^-0.5
                        ((unsigned short*)out0)[(bh * NTOK_P + t) * HD + d] = f2bf(val);
                    } else if (which == 1) {
                        out1[(bh * NTOK_P + t) * HD + d] = f2bf(val);
                    } else {
                        val += bias1[hn];
                        out2[(bh * HD + d) * MPAD + t] = f2bf(val);
                    }
                } else {
                    ((float*)out0)[(size_t)m * DIM + n] = val + bias0[n];
                }
            }
        }
    }
}

// ---------------- fused attention ----------------
// block = one (b,h) x 64 q-rows; 4 waves x 16 q-rows each.

__launch_bounds__(256)
__global__ void attn_kernel(const unsigned short* __restrict__ qbuf, // [BH,208,64]
                            const unsigned short* __restrict__ kbuf, // [BH,208,64]
                            const unsigned short* __restrict__ vt,   // [BH,64,224]
                            const float* __restrict__ rpb,           // [12,208,208]
                            unsigned short* __restrict__ ao)         // [12608,768]
{
    __shared__ __align__(16) unsigned short p_lds[4][16][MPAD];
    int bid = blockIdx.x;
    int qb_i = bid & 3, bh = bid >> 2;
    int b = bh / NH, h = bh - b * NH;
    int tid = threadIdx.x, lane = tid & 63, w = tid >> 6;
    int r0 = qb_i * 64 + w * 16;

    // zero pad columns 208..223 of this wave's P buffer
    {
        int rr = lane >> 2, cc = NTOK_P + (lane & 3) * 4;
        ushort4 z = {0, 0, 0, 0};
        *(ushort4*)&p_lds[w][rr][cc] = z;
    }

    const size_t kqbase = (size_t)bh * NTOK_P * HD;
    int qrow = r0 + (lane & 15); if (qrow > NTOK_P - 1) qrow = NTOK_P - 1;
    bf16x8 qf0 = *(const bf16x8*)&qbuf[kqbase + (size_t)qrow * HD + (lane >> 4) * 8];
    bf16x8 qf1 = *(const bf16x8*)&qbuf[kqbase + (size_t)qrow * HD + 32 + (lane >> 4) * 8];

    // S = (Q*scale) K^T   (13 column tiles of 16)
    f32x4 s[13];
#pragma unroll
    for (int t = 0; t < 13; t++) {
        int krow = t * 16 + (lane & 15);
        bf16x8 kf0 = *(const bf16x8*)&kbuf[kqbase + (size_t)krow * HD + (lane >> 4) * 8];
        bf16x8 kf1 = *(const bf16x8*)&kbuf[kqbase + (size_t)krow * HD + 32 + (lane >> 4) * 8];
        f32x4 z = {0.f, 0.f, 0.f, 0.f};
        f32x4 a = __builtin_amdgcn_mfma_f32_16x16x32_bf16(qf0, kf0, z, 0, 0, 0);
        s[t] = __builtin_amdgcn_mfma_f32_16x16x32_bf16(qf1, kf1, a, 0, 0, 0);
    }

    // + rpb, mask cols >= 197, row max
    int col_l = lane & 15;
    int rbase = r0 + (lane >> 4) * 4;
    float mrow[4] = {-1e30f, -1e30f, -1e30f, -1e30f};
#pragma unroll
    for (int t = 0; t < 13; t++) {
        int col = t * 16 + col_l;
        bool masked = (col >= NTOK);
#pragma unroll
        for (int j = 0; j < 4; j++) {
            int rr = rbase + j; if (rr > NTOK_P - 1) rr = NTOK_P - 1;
            float v = s[t][j] + rpb[((size_t)h * NTOK_P + rr) * NTOK_P + col];
            if (masked) v = -1e30f;
            s[t][j] = v;
            mrow[j] = fmaxf(mrow[j], v);
        }
    }
#pragma unroll
    for (int j = 0; j < 4; j++) {
        float mv = mrow[j];
        mv = fmaxf(mv, __shfl_xor(mv, 1));
        mv = fmaxf(mv, __shfl_xor(mv, 2));
        mv = fmaxf(mv, __shfl_xor(mv, 4));
        mv = fmaxf(mv, __shfl_xor(mv, 8));
        mrow[j] = mv;
    }
    float lrow[4] = {0.f, 0.f, 0.f, 0.f};
#pragma unroll
    for (int t = 0; t < 13; t++)
#pragma unroll
        for (int j = 0; j < 4; j++) {
            float p = __expf(s[t][j] - mrow[j]);
            s[t][j] = p;
            lrow[j] += p;
        }
#pragma unroll
    for (int j = 0; j < 4; j++) {
        float lv = lrow[j];
        lv += __shfl_xor(lv, 1);
        lv += __shfl_xor(lv, 2);
        lv += __shfl_xor(lv, 4);
        lv += __shfl_xor(lv, 8);
        lrow[j] = lv;
    }
    // P -> LDS (bf16), C-layout scatter
#pragma unroll
    for (int t = 0; t < 13; t++)
#pragma unroll
        for (int j = 0; j < 4; j++)
            p_lds[w][(lane >> 4) * 4 + j][t * 16 + col_l] = f2bf(s[t][j]);

    __syncthreads();

    // O = P V   (A-frags from LDS, B-frags from v^T global)
    f32x4 o[4] = {};
    const size_t vbase = (size_t)bh * HD * MPAD;
#pragma unroll
    for (int c = 0; c < 7; c++) {
        bf16x8 pf = *(const bf16x8*)&p_lds[w][lane & 15][c * 32 + (lane >> 4) * 8];
#pragma unroll
        for (int n = 0; n < 4; n++) {
            bf16x8 vf = *(const bf16x8*)&vt[vbase + (size_t)(n * 16 + (lane & 15)) * MPAD + c * 32 + (lane >> 4) * 8];
            o[n] = __builtin_amdgcn_mfma_f32_16x16x32_bf16(pf, vf, o[n], 0, 0, 0);
        }
    }
#pragma unroll
    for (int n = 0; n < 4; n++)
#pragma unroll
        for (int j = 0; j < 4; j++) {
            int tok = rbase + j;
            if (tok < NTOK) {
                float val = o[n][j] / lrow[j];
                ao[((size_t)b * NTOK + tok) * DIM + h * HD + n * 16 + col_l] = f2bf(val);
            }
        }
}

// ---------------- launcher ----------------

extern "C" void kernel_launch(void* const* d_in, const int* in_sizes, int n_in,
                              void* d_out, int out_size, void* d_ws, size_t ws_size,
                              hipStream_t stream)
{
    const float* x      = (const float*)d_in[0];
    const float* qkv_w  = (const float*)d_in[1];
    const float* q_bias = (const float*)d_in[2];
    const float* v_bias = (const float*)d_in[3];
    const float* rpb_t  = (const float*)d_in[4];
    const float* proj_w = (const float*)d_in[5];
    const float* proj_b = (const float*)d_in[6];
    const int*   relidx = (const int*)d_in[7];
    float* out = (float*)d_out;

    char* ws = (char*)d_ws;
    const size_t SZ_XBF  = (size_t)MROWS * DIM * 2;              // 19,365,888 (also reused as attn-out)
    const size_t SZ_QKVW = (size_t)3 * DIM * DIM * 2;            // 3,538,944
    const size_t SZ_PRJW = (size_t)DIM * DIM * 2;                // 1,179,648
    const size_t SZ_QK   = (size_t)BATCH * NH * NTOK_P * HD * 2; // 20,447,232
    const size_t SZ_VT   = (size_t)BATCH * NH * HD * MPAD * 2;   // 22,020,096

    unsigned short* x_bf = (unsigned short*)ws;
    unsigned short* ao   = x_bf; // aliased: x_bf dead after QKV gemm
    size_t off = SZ_XBF;
    unsigned short* qkvw_bf  = (unsigned short*)(ws + off); off += SZ_QKVW;
    unsigned short* projw_bf = (unsigned short*)(ws + off); off += SZ_PRJW;
    unsigned short* qbuf     = (unsigned short*)(ws + off); off += SZ_QK;
    unsigned short* kbuf     = (unsigned short*)(ws + off); off += SZ_QK;
    unsigned short* vtbuf    = (unsigned short*)(ws + off); off += SZ_VT;
    float* rpbf              = (float*)(ws + off);

    // prep
    cvt_bf16_kernel<<<(MROWS * DIM / 4 + 255) / 256, 256, 0, stream>>>(x, x_bf, MROWS * DIM / 4);
    cvt_bf16_kernel<<<(3 * DIM * DIM / 4 + 255) / 256, 256, 0, stream>>>(qkv_w, qkvw_bf, 3 * DIM * DIM / 4);
    cvt_bf16_kernel<<<(DIM * DIM / 4 + 255) / 256, 256, 0, stream>>>(proj_w, projw_bf, DIM * DIM / 4);
    build_rpb_kernel<<<(NH * NTOK_P * NTOK_P + 255) / 256, 256, 0, stream>>>(rpb_t, relidx, rpbf);
    zero_vt_pad_kernel<<<(BATCH * NH * HD * (MPAD - NTOK) + 255) / 256, 256, 0, stream>>>(vtbuf);

    // QKV gemm: M=12608, N=2304 (18 n-tiles), fused bias/scale + scatter to q/k/v^T
    gemm_bt_kernel<0><<<99 * 18, 256, 0, stream>>>(x_bf, qkvw_bf, q_bias, v_bias,
                                                   (void*)qbuf, kbuf, vtbuf, MROWS, 18);
    // fused attention
    attn_kernel<<<BATCH * NH * 4, 256, 0, stream>>>(qbuf, kbuf, vtbuf, rpbf, ao);
    // proj gemm: M=12608, N=768 (6 n-tiles), fp32 out + bias
    gemm_bt_kernel<1><<<99 * 6, 256, 0, stream>>>(ao, projw_bf, proj_b, nullptr,
                                                  (void*)out, nullptr, nullptr, MROWS, 6);
    (void)in_sizes; (void)n_in; (void)out_size; (void)ws_size;
}

// Round 2
// 264.070 us; speedup vs baseline: 1.0446x; 1.0446x over previous
//
#include <hip/hip_runtime.h>
#include <hip/hip_bf16.h>
#include <cstdint>
#include <cstddef>

typedef __bf16 bf16x8 __attribute__((ext_vector_type(8)));
typedef float f32x4 __attribute__((ext_vector_type(4)));

#define DI __device__ __forceinline__

DI unsigned short f2bf(float x) {
    union { float f; unsigned int u; } v; v.f = x;
    unsigned int u = v.u;
    u += 0x7FFFu + ((u >> 16) & 1u);
    return (unsigned short)(u >> 16);
}

#define BATCH 64
#define NH 12
#define NTOK 197
#define NTOK_P 208   // 13*16
#define HD 64
#define DIM 768
#define MROWS 12608  // BATCH*NTOK
#define MPAD 224     // 7*32 padded kv length for PV
#define PLDS 232     // padded P row stride (bank-conflict-free: 464B ≡ 20 dwords mod 32)

// ---------------- prep kernels ----------------

__global__ void cvt_bf16_kernel(const float* __restrict__ in, unsigned short* __restrict__ out, int n4) {
    int i = blockIdx.x * blockDim.x + threadIdx.x;
    if (i >= n4) return;
    float4 f = ((const float4*)in)[i];
    ushort4 o;
    o.x = f2bf(f.x); o.y = f2bf(f.y); o.z = f2bf(f.z); o.w = f2bf(f.w);
    ((ushort4*)out)[i] = o;
}

// rpb transposed: out[h][col][row] so attn reads float4 along rows
__global__ void build_rpb_kernel(const float* __restrict__ table, const int* __restrict__ idx,
                                 float* __restrict__ out) {
    int i = blockIdx.x * blockDim.x + threadIdx.x;
    if (i >= NH * NTOK_P * NTOK_P) return;
    int r = i % NTOK_P; int c = (i / NTOK_P) % NTOK_P; int h = i / (NTOK_P * NTOK_P);
    float v = 0.f;
    if (r < NTOK && c < NTOK) v = table[idx[r * NTOK + c] * NH + h];
    out[i] = v;
}

__global__ void zero_vt_pad_kernel(unsigned short* __restrict__ vt) {
    const int npad = MPAD - NTOK; // 27
    int i = blockIdx.x * blockDim.x + threadIdx.x;
    if (i >= BATCH * NH * HD * npad) return;
    int c = NTOK + (i % npad);
    int row = i / npad;
    vt[(size_t)row * MPAD + c] = 0;
}

// ---------------- NT GEMM: C[m,n] = sum_k A[m,k]*W[n,k], K=768 ----------------
// LDS tiles [128][64] bf16 with XOR swizzle: phys_byte = log_byte ^ ((row&7)<<4).
// global_load_lds writes linearly, so the SOURCE column is pre-swizzled (rule #21).
// EPI 0: qkv epilogue (bias + scale, scatter to q/k/vt bf16)
// EPI 1: proj epilogue (bias, fp32 to d_out)

DI int swz(int row, int col_elem) {
    return (row * 64 + col_elem) ^ ((row & 7) << 3);
}

template<int EPI>
__launch_bounds__(256)
__global__ void gemm_bt_kernel(const unsigned short* __restrict__ A,
                               const unsigned short* __restrict__ W,
                               const float* __restrict__ bias0,
                               const float* __restrict__ bias1,
                               void* __restrict__ out0,
                               unsigned short* __restrict__ out1,
                               unsigned short* __restrict__ out2,
                               int M, int ntiles)
{
    __shared__ __align__(16) unsigned short As[128 * 64];
    __shared__ __align__(16) unsigned short Bs[128 * 64];
    const int K = DIM;
    int bid = blockIdx.x;
    int mt = bid / ntiles, nt = bid % ntiles;
    int m0 = mt * 128, n0 = nt * 128;
    int tid = threadIdx.x;
    int lane = tid & 63, w = tid >> 6;
    int wr = (w >> 1) * 64, wc = (w & 1) * 64;

    // staging geometry: subtile s covers rows s*8..s*8+7; lane -> row s*8+(lane>>3),
    // source col pre-swizzled: ((lane&7) ^ (lane>>3)) * 8 elements
    const int st_row = lane >> 3;
    const int st_col = ((lane & 7) ^ (lane >> 3)) << 3;

    f32x4 acc[4][4] = {};

    for (int ks = 0; ks < K; ks += 64) {
#pragma unroll
        for (int i = 0; i < 4; i++) {
            int s = w * 4 + i;
            int arow = m0 + s * 8 + st_row; if (arow >= M) arow = M - 1;
            __builtin_amdgcn_global_load_lds(
                (const __attribute__((address_space(1))) void*)(A + (size_t)arow * K + ks + st_col),
                (__attribute__((address_space(3))) void*)(As + s * 512),
                16, 0, 0);
        }
#pragma unroll
        for (int i = 0; i < 4; i++) {
            int s = w * 4 + i;
            __builtin_amdgcn_global_load_lds(
                (const __attribute__((address_space(1))) void*)(W + (size_t)(n0 + s * 8 + st_row) * K + ks + st_col),
                (__attribute__((address_space(3))) void*)(Bs + s * 512),
                16, 0, 0);
        }
        __syncthreads();
#pragma unroll
        for (int kc = 0; kc < 2; kc++) {
            bf16x8 af[4], bfr[4];
#pragma unroll
            for (int x = 0; x < 4; x++)
                af[x] = *(const bf16x8*)&As[swz(wr + x * 16 + (lane & 15), kc * 32 + (lane >> 4) * 8)];
#pragma unroll
            for (int y = 0; y < 4; y++)
                bfr[y] = *(const bf16x8*)&Bs[swz(wc + y * 16 + (lane & 15), kc * 32 + (lane >> 4) * 8)];
#pragma unroll
            for (int x = 0; x < 4; x++)
#pragma unroll
                for (int y = 0; y < 4; y++)
                    acc[x][y] = __builtin_amdgcn_mfma_f32_16x16x32_bf16(af[x], bfr[y], acc[x][y], 0, 0, 0);
        }
        __syncthreads();
    }

#pragma unroll
    for (int x = 0; x < 4; x++) {
#pragma unroll
        for (int y = 0; y < 4; y++) {
#pragma unroll
            for (int j = 0; j < 4; j++) {
                int m = m0 + wr + x * 16 + (lane >> 4) * 4 + j;
                int n = n0 + wc + y * 16 + (lane & 15);
                if (m >= M) continue;
                float val = acc[x][y][j];
                if constexpr (EPI == 0) {
                    int b = m / NTOK, t = m - (m / NTOK) * NTOK;
                    int which = n / DIM;
                    int hn = n - which * DIM;
                    int h = hn >> 6, d = hn & 63;
                    size_t bh = (size_t)b * NH + h;
                    if (which == 0) {
                        val = (val + bias0[hn]) * 0.125f; // 64^-0.5
                        ((unsigned short*)out0)[(bh * NTOK_P + t) * HD + d] = f2bf(val);
                    } else if (which == 1) {
                        out1[(bh * NTOK_P + t) * HD + d] = f2bf(val);
                    } else {
                        val += bias1[hn];
                        out2[(bh * HD + d) * MPAD + t] = f2bf(val);
                    }
                } else {
                    ((float*)out0)[(size_t)m * DIM + n] = val + bias0[n];
                }
            }
        }
    }
}

// ---------------- fused attention ----------------
// block = one wave = one (b,h) x 16 q-rows. grid = BH * 13.

__launch_bounds__(64)
__global__ void attn_kernel(const unsigned short* __restrict__ qbuf, // [BH,208,64]
                            const unsigned short* __restrict__ kbuf, // [BH,208,64]
                            const unsigned short* __restrict__ vt,   // [BH,64,224]
                            const float* __restrict__ rpbT,          // [12,208(col),208(row)]
                            unsigned short* __restrict__ ao)         // [12608,768]
{
    __shared__ __align__(16) unsigned short p_lds[16][PLDS];
    int bid = blockIdx.x;
    int qt = bid % 13, bh = bid / 13;
    int b = bh / NH, h = bh - b * NH;
    int lane = threadIdx.x;
    int r0 = qt * 16;

    // zero pad columns 208..223 of the P buffer (read by PV but never written)
    {
        int rr = lane >> 2, cc = NTOK_P + (lane & 3) * 4;
        ushort4 z = {0, 0, 0, 0};
        *(ushort4*)&p_lds[rr][cc] = z;
    }

    const size_t kqbase = (size_t)bh * NTOK_P * HD;
    int qrow = r0 + (lane & 15);
    bf16x8 qf0 = *(const bf16x8*)&qbuf[kqbase + (size_t)qrow * HD + (lane >> 4) * 8];
    bf16x8 qf1 = *(const bf16x8*)&qbuf[kqbase + (size_t)qrow * HD + 32 + (lane >> 4) * 8];

    // S = (Q*scale) K^T   (13 column tiles of 16)
    f32x4 s[13];
#pragma unroll
    for (int t = 0; t < 13; t++) {
        int krow = t * 16 + (lane & 15);
        bf16x8 kf0 = *(const bf16x8*)&kbuf[kqbase + (size_t)krow * HD + (lane >> 4) * 8];
        bf16x8 kf1 = *(const bf16x8*)&kbuf[kqbase + (size_t)krow * HD + 32 + (lane >> 4) * 8];
        f32x4 z = {0.f, 0.f, 0.f, 0.f};
        f32x4 a = __builtin_amdgcn_mfma_f32_16x16x32_bf16(qf0, kf0, z, 0, 0, 0);
        s[t] = __builtin_amdgcn_mfma_f32_16x16x32_bf16(qf1, kf1, a, 0, 0, 0);
    }

    // + rpb (transposed layout -> one float4 per tile), mask cols >= 197, row max
    int col_l = lane & 15;
    int rbase = r0 + (lane >> 4) * 4;
    float mrow[4] = {-1e30f, -1e30f, -1e30f, -1e30f};
#pragma unroll
    for (int t = 0; t < 13; t++) {
        int col = t * 16 + col_l;
        bool masked = (col >= NTOK);
        float4 rb = *(const float4*)&rpbT[((size_t)h * NTOK_P + col) * NTOK_P + rbase];
        float rbj[4] = {rb.x, rb.y, rb.z, rb.w};
#pragma unroll
        for (int j = 0; j < 4; j++) {
            float v = s[t][j] + rbj[j];
            if (masked) v = -1e30f;
            s[t][j] = v;
            mrow[j] = fmaxf(mrow[j], v);
        }
    }
#pragma unroll
    for (int j = 0; j < 4; j++) {
        float mv = mrow[j];
        mv = fmaxf(mv, __shfl_xor(mv, 1));
        mv = fmaxf(mv, __shfl_xor(mv, 2));
        mv = fmaxf(mv, __shfl_xor(mv, 4));
        mv = fmaxf(mv, __shfl_xor(mv, 8));
        mrow[j] = mv;
    }
    float lrow[4] = {0.f, 0.f, 0.f, 0.f};
#pragma unroll
    for (int t = 0; t < 13; t++)
#pragma unroll
        for (int j = 0; j < 4; j++) {
            float p = __expf(s[t][j] - mrow[j]);
            s[t][j] = p;
            lrow[j] += p;
        }
#pragma unroll
    for (int j = 0; j < 4; j++) {
        float lv = lrow[j];
        lv += __shfl_xor(lv, 1);
        lv += __shfl_xor(lv, 2);
        lv += __shfl_xor(lv, 4);
        lv += __shfl_xor(lv, 8);
        lrow[j] = lv;
    }
    // P -> LDS (bf16), C-layout scatter (wave-private, no barrier needed)
#pragma unroll
    for (int t = 0; t < 13; t++)
#pragma unroll
        for (int j = 0; j < 4; j++)
            p_lds[(lane >> 4) * 4 + j][t * 16 + col_l] = f2bf(s[t][j]);

    // O = P V   (A-frags from LDS, B-frags from v^T global)
    f32x4 o[4] = {};
    const size_t vbase = (size_t)bh * HD * MPAD;
#pragma unroll
    for (int c = 0; c < 7; c++) {
        bf16x8 pf = *(const bf16x8*)&p_lds[lane & 15][c * 32 + (lane >> 4) * 8];
#pragma unroll
        for (int n = 0; n < 4; n++) {
            bf16x8 vf = *(const bf16x8*)&vt[vbase + (size_t)(n * 16 + (lane & 15)) * MPAD + c * 32 + (lane >> 4) * 8];
            o[n] = __builtin_amdgcn_mfma_f32_16x16x32_bf16(pf, vf, o[n], 0, 0, 0);
        }
    }
#pragma unroll
    for (int n = 0; n < 4; n++)
#pragma unroll
        for (int j = 0; j < 4; j++) {
            int tok = rbase + j;
            if (tok < NTOK) {
                float val = o[n][j] / lrow[j];
                ao[((size_t)b * NTOK + tok) * DIM + h * HD + n * 16 + col_l] = f2bf(val);
            }
        }
}

// ---------------- launcher ----------------

extern "C" void kernel_launch(void* const* d_in, const int* in_sizes, int n_in,
                              void* d_out, int out_size, void* d_ws, size_t ws_size,
                              hipStream_t stream)
{
    const float* x      = (const float*)d_in[0];
    const float* qkv_w  = (const float*)d_in[1];
    const float* q_bias = (const float*)d_in[2];
    const float* v_bias = (const float*)d_in[3];
    const float* rpb_t  = (const float*)d_in[4];
    const float* proj_w = (const float*)d_in[5];
    const float* proj_b = (const float*)d_in[6];
    const int*   relidx = (const int*)d_in[7];
    float* out = (float*)d_out;

    char* ws = (char*)d_ws;
    const size_t SZ_XBF  = (size_t)MROWS * DIM * 2;              // also reused as attn-out
    const size_t SZ_QKVW = (size_t)3 * DIM * DIM * 2;
    const size_t SZ_PRJW = (size_t)DIM * DIM * 2;
    const size_t SZ_QK   = (size_t)BATCH * NH * NTOK_P * HD * 2;
    const size_t SZ_VT   = (size_t)BATCH * NH * HD * MPAD * 2;

    unsigned short* x_bf = (unsigned short*)ws;
    unsigned short* ao   = x_bf; // aliased: x_bf dead after QKV gemm
    size_t off = SZ_XBF;
    unsigned short* qkvw_bf  = (unsigned short*)(ws + off); off += SZ_QKVW;
    unsigned short* projw_bf = (unsigned short*)(ws + off); off += SZ_PRJW;
    unsigned short* qbuf     = (unsigned short*)(ws + off); off += SZ_QK;
    unsigned short* kbuf     = (unsigned short*)(ws + off); off += SZ_QK;
    unsigned short* vtbuf    = (unsigned short*)(ws + off); off += SZ_VT;
    float* rpbf              = (float*)(ws + off);

    // prep
    cvt_bf16_kernel<<<(MROWS * DIM / 4 + 255) / 256, 256, 0, stream>>>(x, x_bf, MROWS * DIM / 4);
    cvt_bf16_kernel<<<(3 * DIM * DIM / 4 + 255) / 256, 256, 0, stream>>>(qkv_w, qkvw_bf, 3 * DIM * DIM / 4);
    cvt_bf16_kernel<<<(DIM * DIM / 4 + 255) / 256, 256, 0, stream>>>(proj_w, projw_bf, DIM * DIM / 4);
    build_rpb_kernel<<<(NH * NTOK_P * NTOK_P + 255) / 256, 256, 0, stream>>>(rpb_t, relidx, rpbf);
    zero_vt_pad_kernel<<<(BATCH * NH * HD * (MPAD - NTOK) + 255) / 256, 256, 0, stream>>>(vtbuf);

    // QKV gemm: M=12608, N=2304 (18 n-tiles), fused bias/scale + scatter to q/k/v^T
    gemm_bt_kernel<0><<<99 * 18, 256, 0, stream>>>(x_bf, qkvw_bf, q_bias, v_bias,
                                                   (void*)qbuf, kbuf, vtbuf, MROWS, 18);
    // fused attention: one wave per 16 q-rows
    attn_kernel<<<BATCH * NH * 13, 64, 0, stream>>>(qbuf, kbuf, vtbuf, rpbf, ao);
    // proj gemm: M=12608, N=768 (6 n-tiles), fp32 out + bias
    gemm_bt_kernel<1><<<99 * 6, 256, 0, stream>>>(ao, projw_bf, proj_b, nullptr,
                                                  (void*)out, nullptr, nullptr, MROWS, 6);
    (void)in_sizes; (void)n_in; (void)out_size; (void)ws_size;
}

// Round 3
// 207.451 us; speedup vs baseline: 1.3297x; 1.2729x over previous
//
#include <hip/hip_runtime.h>
#include <hip/hip_bf16.h>
#include <cstdint>
#include <cstddef>

typedef __bf16 bf16x8 __attribute__((ext_vector_type(8)));
typedef float f32x4 __attribute__((ext_vector_type(4)));

#define DI __device__ __forceinline__

DI unsigned short f2bf(float x) {
    union { float f; unsigned int u; } v; v.f = x;
    unsigned int u = v.u;
    u += 0x7FFFu + ((u >> 16) & 1u);
    return (unsigned short)(u >> 16);
}

#define BATCH 64
#define NH 12
#define NTOK 197
#define NTOK_P 208   // 13*16
#define HD 64
#define DIM 768
#define MROWS 12608  // BATCH*NTOK
#define MPAD 224     // 7*32 padded kv length for PV
#define PLDS 232     // padded P row stride in attn
#define CPAD 132     // epilogue LDS row stride (ushort): 264B rows, 8B-aligned, ~2-4-way banks

// bijective XCD-aware swizzle (m204): same-XCD blocks get contiguous wgid chunk
DI int xcd_swz(int orig, int nwg) {
    int q = nwg >> 3, r = nwg & 7;
    int x = orig & 7, l = orig >> 3;
    return (x < r ? x * (q + 1) : r * (q + 1) + (x - r) * q) + l;
}

// ---------------- prep kernels ----------------

__global__ void cvt_bf16_kernel(const float* __restrict__ in, unsigned short* __restrict__ out, int n4) {
    int i = blockIdx.x * blockDim.x + threadIdx.x;
    if (i >= n4) return;
    float4 f = ((const float4*)in)[i];
    ushort4 o;
    o.x = f2bf(f.x); o.y = f2bf(f.y); o.z = f2bf(f.z); o.w = f2bf(f.w);
    ((ushort4*)out)[i] = o;
}

// rpb transposed: out[h][col][row] so attn reads float4 along rows
__global__ void build_rpb_kernel(const float* __restrict__ table, const int* __restrict__ idx,
                                 float* __restrict__ out) {
    int i = blockIdx.x * blockDim.x + threadIdx.x;
    if (i >= NH * NTOK_P * NTOK_P) return;
    int r = i % NTOK_P; int c = (i / NTOK_P) % NTOK_P; int h = i / (NTOK_P * NTOK_P);
    float v = 0.f;
    if (r < NTOK && c < NTOK) v = table[idx[r * NTOK + c] * NH + h];
    out[i] = v;
}

__global__ void zero_vt_pad_kernel(unsigned short* __restrict__ vt) {
    const int npad = MPAD - NTOK; // 27
    int i = blockIdx.x * blockDim.x + threadIdx.x;
    if (i >= BATCH * NH * HD * npad) return;
    int c = NTOK + (i % npad);
    int row = i / npad;
    vt[(size_t)row * MPAD + c] = 0;
}

// ---------------- NT GEMM: C[m,n] = sum_k A[m,k]*W[n,k], K=768 ----------------
// 2-phase double-buffered (T3-min): STAGE(next) issued BEFORE compute(cur),
// one vmcnt(0)-barrier per K-tile. LDS XOR-swizzle (T2) via pre-swizzled source.
// EPI 0: qkv epilogue (bias+scale, LDS-retile, coalesced q/k/vt stores)
// EPI 1: proj epilogue (bias, fp32 direct to d_out)

DI int swz(int row, int col_elem) {
    return (row * 64 + col_elem) ^ ((row & 7) << 3);
}

template<int EPI>
__launch_bounds__(256)
__global__ void gemm_bt_kernel(const unsigned short* __restrict__ A,
                               const unsigned short* __restrict__ W,
                               const float* __restrict__ bias0,
                               const float* __restrict__ bias1,
                               void* __restrict__ out0,
                               unsigned short* __restrict__ out1,
                               unsigned short* __restrict__ out2,
                               int M, int ntiles)
{
    __shared__ __align__(16) unsigned short smem[32768]; // 64 KB: As[2]|Bs[2], reused by epilogue
    const int K = DIM;
    const int NT = K / 64; // 12
    int wgid = xcd_swz(blockIdx.x, gridDim.x);
    int mt = wgid / ntiles, nt = wgid % ntiles;
    int m0 = mt * 128, n0 = nt * 128;
    int tid = threadIdx.x;
    int lane = tid & 63, w = tid >> 6;
    int wr = (w >> 1) * 64, wc = (w & 1) * 64;

    const int st_row = lane >> 3;
    const int st_col = ((lane & 7) ^ (lane >> 3)) << 3; // pre-swizzled source column

    f32x4 acc[4][4] = {};

    auto stage = [&](int buf, int ks) {
        unsigned short* as = smem + buf * 8192;
        unsigned short* bs = smem + 16384 + buf * 8192;
#pragma unroll
        for (int i = 0; i < 4; i++) {
            int s = w * 4 + i;
            int arow = m0 + s * 8 + st_row; if (arow >= M) arow = M - 1;
            __builtin_amdgcn_global_load_lds(
                (const __attribute__((address_space(1))) void*)(A + (size_t)arow * K + ks + st_col),
                (__attribute__((address_space(3))) void*)(as + s * 512), 16, 0, 0);
        }
#pragma unroll
        for (int i = 0; i < 4; i++) {
            int s = w * 4 + i;
            __builtin_amdgcn_global_load_lds(
                (const __attribute__((address_space(1))) void*)(W + (size_t)(n0 + s * 8 + st_row) * K + ks + st_col),
                (__attribute__((address_space(3))) void*)(bs + s * 512), 16, 0, 0);
        }
    };

    stage(0, 0);
    __syncthreads();
    int cur = 0;
    for (int t = 0; t < NT; ++t) {
        if (t + 1 < NT) stage(cur ^ 1, (t + 1) * 64);
        const unsigned short* as = smem + cur * 8192;
        const unsigned short* bs = smem + 16384 + cur * 8192;
#pragma unroll
        for (int kc = 0; kc < 2; kc++) {
            bf16x8 af[4], bfr[4];
#pragma unroll
            for (int x = 0; x < 4; x++)
                af[x] = *(const bf16x8*)&as[swz(wr + x * 16 + (lane & 15), kc * 32 + (lane >> 4) * 8)];
#pragma unroll
            for (int y = 0; y < 4; y++)
                bfr[y] = *(const bf16x8*)&bs[swz(wc + y * 16 + (lane & 15), kc * 32 + (lane >> 4) * 8)];
#pragma unroll
            for (int x = 0; x < 4; x++)
#pragma unroll
                for (int y = 0; y < 4; y++)
                    acc[x][y] = __builtin_amdgcn_mfma_f32_16x16x32_bf16(af[x], bfr[y], acc[x][y], 0, 0, 0);
        }
        __syncthreads(); // drains vmcnt(0): next buf staged; all waves done reading cur
        cur ^= 1;
    }

    if constexpr (EPI == 1) {
        // proj: fp32 direct stores (64B segments)
#pragma unroll
        for (int x = 0; x < 4; x++)
#pragma unroll
            for (int y = 0; y < 4; y++)
#pragma unroll
                for (int j = 0; j < 4; j++) {
                    int m = m0 + wr + x * 16 + (lane >> 4) * 4 + j;
                    int n = n0 + wc + y * 16 + (lane & 15);
                    if (m < M)
                        ((float*)out0)[(size_t)m * DIM + n] = acc[x][y][j] + bias0[n];
                }
    } else {
        // qkv: one 128-tile lies entirely within q, k, or v (768 = 6*128)
        int which = n0 / DIM;
        int hn0 = n0 - which * DIM; // multiple of 128 -> tile covers 2 heads
        unsigned short* lc = smem;  // [128][CPAD] bf16, 33.8 KB

#pragma unroll
        for (int x = 0; x < 4; x++)
#pragma unroll
            for (int y = 0; y < 4; y++)
#pragma unroll
                for (int j = 0; j < 4; j++) {
                    int ml = wr + x * 16 + (lane >> 4) * 4 + j;
                    int nl = wc + y * 16 + (lane & 15);
                    float val = acc[x][y][j];
                    if (which == 0) val = (val + bias0[hn0 + nl]) * 0.125f;
                    else if (which == 2) val = val + bias1[hn0 + nl];
                    lc[ml * CPAD + nl] = f2bf(val);
                }
        __syncthreads();

        if (which != 2) {
            // q/k: [BH,208,64]; per wave-instr: 4x 128B coalesced segments
            unsigned short* outq = (which == 0) ? (unsigned short*)out0 : out1;
            int c4 = (lane & 31) * 4;
            int h = (hn0 >> 6) + (c4 >> 6), d = c4 & 63;
            for (int it = 0; it < 16; ++it) {
                int r = it * 8 + w * 2 + (lane >> 5);
                int m = m0 + r;
                if (m >= M) continue;
                int b = m / NTOK, t = m - b * NTOK;
                ushort4 q4 = *(const ushort4*)&lc[r * CPAD + c4];
                *(ushort4*)&outq[(((size_t)b * NH + h) * NTOK_P + t) * HD + d] = q4;
            }
        } else {
            // v^T: [BH,64,224]; lanes are consecutive t -> coalesced along rows
            int mh = w >> 1, hs = w & 1;
            int h = (hn0 >> 6) + hs;
            int ml = mh * 64 + lane;
            int m = m0 + ml;
            if (m < M) {
                int b = m / NTOK, t = m - b * NTOK;
                unsigned short* vbase = out2 + (((size_t)b * NH + h) * HD) * MPAD + t;
#pragma unroll 8
                for (int d = 0; d < 64; ++d)
                    vbase[(size_t)d * MPAD] = lc[ml * CPAD + hs * 64 + d];
            }
        }
    }
}

// ---------------- fused attention ----------------
// block = one wave = one (b,h) x 16 q-rows. grid = BH * 13.

__launch_bounds__(64)
__global__ void attn_kernel(const unsigned short* __restrict__ qbuf, // [BH,208,64]
                            const unsigned short* __restrict__ kbuf, // [BH,208,64]
                            const unsigned short* __restrict__ vt,   // [BH,64,224]
                            const float* __restrict__ rpbT,          // [12,208(col),208(row)]
                            unsigned short* __restrict__ ao)         // [12608,768]
{
    __shared__ __align__(16) unsigned short p_lds[16][PLDS];
    int bid = xcd_swz(blockIdx.x, gridDim.x); // 13 blocks per bh stay on one XCD
    int qt = bid % 13, bh = bid / 13;
    int b = bh / NH, h = bh - b * NH;
    int lane = threadIdx.x;
    int r0 = qt * 16;

    // zero pad columns 208..223 of the P buffer (read by PV but never written)
    {
        int rr = lane >> 2, cc = NTOK_P + (lane & 3) * 4;
        ushort4 z = {0, 0, 0, 0};
        *(ushort4*)&p_lds[rr][cc] = z;
    }

    const size_t kqbase = (size_t)bh * NTOK_P * HD;
    int qrow = r0 + (lane & 15);
    bf16x8 qf0 = *(const bf16x8*)&qbuf[kqbase + (size_t)qrow * HD + (lane >> 4) * 8];
    bf16x8 qf1 = *(const bf16x8*)&qbuf[kqbase + (size_t)qrow * HD + 32 + (lane >> 4) * 8];

    // S = (Q*scale) K^T   (13 column tiles of 16)
    f32x4 s[13];
#pragma unroll
    for (int t = 0; t < 13; t++) {
        int krow = t * 16 + (lane & 15);
        bf16x8 kf0 = *(const bf16x8*)&kbuf[kqbase + (size_t)krow * HD + (lane >> 4) * 8];
        bf16x8 kf1 = *(const bf16x8*)&kbuf[kqbase + (size_t)krow * HD + 32 + (lane >> 4) * 8];
        f32x4 z = {0.f, 0.f, 0.f, 0.f};
        f32x4 a = __builtin_amdgcn_mfma_f32_16x16x32_bf16(qf0, kf0, z, 0, 0, 0);
        s[t] = __builtin_amdgcn_mfma_f32_16x16x32_bf16(qf1, kf1, a, 0, 0, 0);
    }

    // + rpb (transposed layout -> one float4 per tile), mask cols >= 197, row max
    int col_l = lane & 15;
    int rbase = r0 + (lane >> 4) * 4;
    float mrow[4] = {-1e30f, -1e30f, -1e30f, -1e30f};
#pragma unroll
    for (int t = 0; t < 13; t++) {
        int col = t * 16 + col_l;
        bool masked = (col >= NTOK);
        float4 rb = *(const float4*)&rpbT[((size_t)h * NTOK_P + col) * NTOK_P + rbase];
        float rbj[4] = {rb.x, rb.y, rb.z, rb.w};
#pragma unroll
        for (int j = 0; j < 4; j++) {
            float v = s[t][j] + rbj[j];
            if (masked) v = -1e30f;
            s[t][j] = v;
            mrow[j] = fmaxf(mrow[j], v);
        }
    }
#pragma unroll
    for (int j = 0; j < 4; j++) {
        float mv = mrow[j];
        mv = fmaxf(mv, __shfl_xor(mv, 1));
        mv = fmaxf(mv, __shfl_xor(mv, 2));
        mv = fmaxf(mv, __shfl_xor(mv, 4));
        mv = fmaxf(mv, __shfl_xor(mv, 8));
        mrow[j] = mv;
    }
    float lrow[4] = {0.f, 0.f, 0.f, 0.f};
#pragma unroll
    for (int t = 0; t < 13; t++)
#pragma unroll
        for (int j = 0; j < 4; j++) {
            float p = __expf(s[t][j] - mrow[j]);
            s[t][j] = p;
            lrow[j] += p;
        }
#pragma unroll
    for (int j = 0; j < 4; j++) {
        float lv = lrow[j];
        lv += __shfl_xor(lv, 1);
        lv += __shfl_xor(lv, 2);
        lv += __shfl_xor(lv, 4);
        lv += __shfl_xor(lv, 8);
        lrow[j] = lv;
    }
    // P -> LDS (bf16), C-layout scatter (wave-private, no barrier needed)
#pragma unroll
    for (int t = 0; t < 13; t++)
#pragma unroll
        for (int j = 0; j < 4; j++)
            p_lds[(lane >> 4) * 4 + j][t * 16 + col_l] = f2bf(s[t][j]);

    // O = P V   (A-frags from LDS, B-frags from v^T global)
    f32x4 o[4] = {};
    const size_t vbase = (size_t)bh * HD * MPAD;
#pragma unroll
    for (int c = 0; c < 7; c++) {
        bf16x8 pf = *(const bf16x8*)&p_lds[lane & 15][c * 32 + (lane >> 4) * 8];
#pragma unroll
        for (int n = 0; n < 4; n++) {
            bf16x8 vf = *(const bf16x8*)&vt[vbase + (size_t)(n * 16 + (lane & 15)) * MPAD + c * 32 + (lane >> 4) * 8];
            o[n] = __builtin_amdgcn_mfma_f32_16x16x32_bf16(pf, vf, o[n], 0, 0, 0);
        }
    }
#pragma unroll
    for (int n = 0; n < 4; n++)
#pragma unroll
        for (int j = 0; j < 4; j++) {
            int tok = rbase + j;
            if (tok < NTOK) {
                float val = o[n][j] / lrow[j];
                ao[((size_t)b * NTOK + tok) * DIM + h * HD + n * 16 + col_l] = f2bf(val);
            }
        }
}

// ---------------- launcher ----------------

extern "C" void kernel_launch(void* const* d_in, const int* in_sizes, int n_in,
                              void* d_out, int out_size, void* d_ws, size_t ws_size,
                              hipStream_t stream)
{
    const float* x      = (const float*)d_in[0];
    const float* qkv_w  = (const float*)d_in[1];
    const float* q_bias = (const float*)d_in[2];
    const float* v_bias = (const float*)d_in[3];
    const float* rpb_t  = (const float*)d_in[4];
    const float* proj_w = (const float*)d_in[5];
    const float* proj_b = (const float*)d_in[6];
    const int*   relidx = (const int*)d_in[7];
    float* out = (float*)d_out;

    char* ws = (char*)d_ws;
    const size_t SZ_XBF  = (size_t)MROWS * DIM * 2;              // also reused as attn-out
    const size_t SZ_QKVW = (size_t)3 * DIM * DIM * 2;
    const size_t SZ_PRJW = (size_t)DIM * DIM * 2;
    const size_t SZ_QK   = (size_t)BATCH * NH * NTOK_P * HD * 2;
    const size_t SZ_VT   = (size_t)BATCH * NH * HD * MPAD * 2;

    unsigned short* x_bf = (unsigned short*)ws;
    unsigned short* ao   = x_bf; // aliased: x_bf dead after QKV gemm
    size_t off = SZ_XBF;
    unsigned short* qkvw_bf  = (unsigned short*)(ws + off); off += SZ_QKVW;
    unsigned short* projw_bf = (unsigned short*)(ws + off); off += SZ_PRJW;
    unsigned short* qbuf     = (unsigned short*)(ws + off); off += SZ_QK;
    unsigned short* kbuf     = (unsigned short*)(ws + off); off += SZ_QK;
    unsigned short* vtbuf    = (unsigned short*)(ws + off); off += SZ_VT;
    float* rpbf              = (float*)(ws + off);

    // prep
    cvt_bf16_kernel<<<(MROWS * DIM / 4 + 255) / 256, 256, 0, stream>>>(x, x_bf, MROWS * DIM / 4);
    cvt_bf16_kernel<<<(3 * DIM * DIM / 4 + 255) / 256, 256, 0, stream>>>(qkv_w, qkvw_bf, 3 * DIM * DIM / 4);
    cvt_bf16_kernel<<<(DIM * DIM / 4 + 255) / 256, 256, 0, stream>>>(proj_w, projw_bf, DIM * DIM / 4);
    build_rpb_kernel<<<(NH * NTOK_P * NTOK_P + 255) / 256, 256, 0, stream>>>(rpb_t, relidx, rpbf);
    zero_vt_pad_kernel<<<(BATCH * NH * HD * (MPAD - NTOK) + 255) / 256, 256, 0, stream>>>(vtbuf);

    // QKV gemm: M=12608, N=2304 (18 n-tiles), fused bias/scale + retile to q/k/v^T
    gemm_bt_kernel<0><<<99 * 18, 256, 0, stream>>>(x_bf, qkvw_bf, q_bias, v_bias,
                                                   (void*)qbuf, kbuf, vtbuf, MROWS, 18);
    // fused attention: one wave per 16 q-rows
    attn_kernel<<<BATCH * NH * 13, 64, 0, stream>>>(qbuf, kbuf, vtbuf, rpbf, ao);
    // proj gemm: M=12608, N=768 (6 n-tiles), fp32 out + bias
    gemm_bt_kernel<1><<<99 * 6, 256, 0, stream>>>(ao, projw_bf, proj_b, nullptr,
                                                  (void*)out, nullptr, nullptr, MROWS, 6);
    (void)in_sizes; (void)n_in; (void)out_size; (void)ws_size;
}